// Round 2
// baseline (172.570 us; speedup 1.0000x reference)
//
#include <hip/hip_runtime.h>

#define NG 76
#define NPOS (NG * NG)                       // 5776
#define NC 85                                // 5 + 80
#define NA 3
#define NPB_MAIN 64                          // positions per full tile
#define TILES_MAIN (NPOS / NPB_MAIN)         // 90 full tiles per plane
#define POS_TAIL (TILES_MAIN * NPB_MAIN)     // 5760
#define NPB_TAIL (NPOS - POS_TAIL)           // 16
#define TPP (TILES_MAIN + 1)                 // 91 tiles per plane
#define STRIDE_F 8.0f                        // 608 / 76

typedef float f4 __attribute__((ext_vector_type(4)));

// exp(w) * scaled_anchor * stride == exp(w) * ANCHOR  (scaled = ANCHOR/stride)
__constant__ float c_aw[NA] = {10.0f, 16.0f, 33.0f};
__constant__ float c_ah[NA] = {13.0f, 30.0f, 23.0f};

__device__ __forceinline__ float rcpf(float x) { return __builtin_amdgcn_rcpf(x); }

template<int NPB>
__device__ __forceinline__ void process_tile(const float* __restrict__ in_plane,
                                             float* __restrict__ out_block,
                                             float* lds, int pos0,
                                             float aw, float ah, int t) {
    constexpr int Q  = NPB / 4;              // float4s per channel row (16 or 4)
    constexpr int NV = NC * Q;               // float4 vectors in the tile

    // ---- load phase: 85 rows x Q float4s, scatter-transpose into LDS ----
    for (int v = t; v < NV; v += 256) {
        const int c  = v / Q;                // Q pow2 -> shift
        const int pq = v - c * Q;
        const f4 f = *reinterpret_cast<const f4*>(in_plane + c * NPOS + pq * 4);
        const int pb = pq * 4;
        lds[(pb + 0) * NC + c] = f.x;        // 2-way bank aliasing only (free)
        lds[(pb + 1) * NC + c] = f.y;
        lds[(pb + 2) * NC + c] = f.z;
        lds[(pb + 3) * NC + c] = f.w;
    }
    __syncthreads();

    // ---- store phase: ds_read_b128, single-exp branchless transform ----
    for (int v = t; v < NV; v += 256) {
        const int e0 = v * 4;
        const f4 f = *reinterpret_cast<const f4*>(&lds[e0]);
        const int p0 = (int)((unsigned)e0 / (unsigned)NC);   // magic mul
        const int c0 = e0 - p0 * NC;
        // grid coords for row p0 and (possible wrap) p0+1, once per vector
        const int posA = pos0 + p0;
        const int gyA  = (int)((unsigned)posA / (unsigned)NG);
        const int gxA  = posA - gyA * NG;
        const bool wrapRow = (gxA == NG - 1);
        const float gxAf = (float)gxA, gyAf = (float)gyA;
        const float gxBf = wrapRow ? 0.0f : gxAf + 1.0f;
        const float gyBf = wrapRow ? gyAf + 1.0f : gyAf;

        const float xin[4] = {f.x, f.y, f.z, f.w};
        float res[4];
        int p = p0, c = c0;
        #pragma unroll
        for (int k = 0; k < 4; ++k) {
            const float x    = xin[k];
            const bool iswh  = (c == 2) || (c == 3);
            const bool isxy  = (c < 2);
            const float e    = __expf(iswh ? x : -x);   // ONE transcendental
            const float sg   = rcpf(1.0f + e);
            const float gx   = (p != p0) ? gxBf : gxAf;
            const float gy   = (p != p0) ? gyBf : gyAf;
            const float g    = (c == 0) ? gx : gy;
            const float mul  = isxy ? STRIDE_F : (iswh ? ((c == 2) ? aw : ah) : 1.0f);
            const float add  = isxy ? g * STRIDE_F : 0.0f;
            res[k] = fmaf(iswh ? e : sg, mul, add);
            if (++c == NC) { c = 0; ++p; }
        }
        f4 o = {res[0], res[1], res[2], res[3]};
        __builtin_nontemporal_store(o, reinterpret_cast<f4*>(out_block + e0));
    }
}

__global__ __launch_bounds__(256) void det_kernel(const float* __restrict__ in,
                                                  float* __restrict__ out) {
    __shared__ __align__(16) float lds[NPB_MAIN * NC];   // 21760 B -> 7 blk/CU

    // XCD-aware bijective swizzle (m204): contiguous tile runs per XCD so
    // neighboring tiles (shared 64B half-lines) hit the same L2.
    unsigned bid = blockIdx.x;
    {
        const unsigned nwg = gridDim.x;
        const unsigned q = nwg >> 3, r = nwg & 7;
        const unsigned xcd = bid & 7, seq = bid >> 3;
        bid = (xcd < r ? xcd * (q + 1) : r * (q + 1) + (xcd - r) * q) + seq;
    }

    const int plane = bid / TPP;             // b*NA + a
    const int tile  = bid - plane * TPP;
    const int a     = plane % NA;
    const int t     = threadIdx.x;
    const int pos0  = tile * NPB_MAIN;       // tail tile: 90*64 = 5760

    const float* in_plane  = in  + (size_t)plane * (NC * NPOS) + pos0;
    float*       out_block = out + (size_t)plane * (NPOS * NC) + (size_t)pos0 * NC;
    const float aw = c_aw[a];
    const float ah = c_ah[a];

    if (tile != TILES_MAIN) {                // block-uniform branch
        process_tile<NPB_MAIN>(in_plane, out_block, lds, pos0, aw, ah, t);
    } else {
        process_tile<NPB_TAIL>(in_plane, out_block, lds, pos0, aw, ah, t);
    }
}

extern "C" void kernel_launch(void* const* d_in, const int* in_sizes, int n_in,
                              void* d_out, int out_size, void* d_ws, size_t ws_size,
                              hipStream_t stream) {
    const float* x = (const float*)d_in[0];
    float* out     = (float*)d_out;
    const int nB     = in_sizes[0] / (NA * NC * NPOS);   // 16
    const int blocks = nB * NA * TPP;                    // 48 * 91 = 4368
    det_kernel<<<blocks, 256, 0, stream>>>(x, out);
}

// Round 3
// 162.191 us; speedup vs baseline: 1.0640x; 1.0640x over previous
//
#include <hip/hip_runtime.h>

#define NG 76
#define NPOS (NG * NG)                  // 5776
#define NC 85                           // 5 + 80
#define NA 3
#define SUB 32                          // positions per pipelined subtile
#define NPB (2 * SUB)                   // 64 positions per main block
#define TILES_MAIN (NPOS / NPB)         // 90 full tiles per plane
#define POS_TAIL (TILES_MAIN * NPB)     // 5760
#define NPB_TAIL (NPOS - POS_TAIL)      // 16
#define TPP (TILES_MAIN + 1)            // 91 tiles per plane
#define STRIDE_F 8.0f                   // 608 / 76

typedef float f4 __attribute__((ext_vector_type(4)));

// exp(w) * scaled_anchor * stride == exp(w) * ANCHOR  (scaled = ANCHOR/stride)
__constant__ float c_aw[NA] = {10.0f, 16.0f, 33.0f};
__constant__ float c_ah[NA] = {13.0f, 30.0f, 23.0f};

__device__ __forceinline__ float rcpf(float x) { return __builtin_amdgcn_rcpf(x); }

// ---- issue all global loads for one subtile into registers ----
// clamped index (not predicated): uniform control flow -> compiler can emit
// counted vmcnt so later loads stay in flight across the first subtile's use.
template<int Q, int NIT>
__device__ __forceinline__ void stage_load(const float* __restrict__ src, int t,
                                           f4* reg) {
    #pragma unroll
    for (int i = 0; i < NIT; ++i) {
        const int v  = min(t + i * 256, NC * Q - 1);
        const int c  = v / Q;
        const int pq = v - c * Q;
        reg[i] = *reinterpret_cast<const f4*>(src + c * NPOS + pq * 4);
    }
}

// ---- scatter-transpose registers into LDS (output order: p*NC + c) ----
// duplicate clamped lanes rewrite the same value to the same address: benign.
template<int Q, int NIT>
__device__ __forceinline__ void stage_write(float* lds, int t, const f4* reg) {
    #pragma unroll
    for (int i = 0; i < NIT; ++i) {
        const int v  = min(t + i * 256, NC * Q - 1);
        const int c  = v / Q;
        const int pq = v - c * Q;
        const int pb = pq * 4;
        lds[(pb + 0) * NC + c] = reg[i].x;   // 2-way bank aliasing only (free)
        lds[(pb + 1) * NC + c] = reg[i].y;
        lds[(pb + 2) * NC + c] = reg[i].z;
        lds[(pb + 3) * NC + c] = reg[i].w;
    }
}

// ---- ds_read_b128 + single-exp branchless transform + coalesced store ----
template<int Q, int NIT>
__device__ __forceinline__ void compute_store(const float* lds,
                                              float* __restrict__ out_sub,
                                              int pos_base, float aw, float ah,
                                              int t) {
    #pragma unroll
    for (int i = 0; i < NIT; ++i) {
        const int v  = min(t + i * 256, NC * Q - 1);
        const int e0 = v * 4;
        const f4 f = *reinterpret_cast<const f4*>(&lds[e0]);
        const int p0 = (int)((unsigned)e0 / (unsigned)NC);   // magic mul
        const int c0 = e0 - p0 * NC;
        // grid coords for row p0 and (possible wrap) p0+1, once per vector
        const int posA = pos_base + p0;
        const int gyA  = (int)((unsigned)posA / (unsigned)NG);
        const int gxA  = posA - gyA * NG;
        const bool wrapRow = (gxA == NG - 1);
        const float gxAf = (float)gxA, gyAf = (float)gyA;
        const float gxBf = wrapRow ? 0.0f : gxAf + 1.0f;
        const float gyBf = wrapRow ? gyAf + 1.0f : gyAf;

        const float xin[4] = {f.x, f.y, f.z, f.w};
        float res[4];
        int p = p0, c = c0;
        #pragma unroll
        for (int k = 0; k < 4; ++k) {
            const float x    = xin[k];
            const bool iswh  = (c == 2) || (c == 3);
            const bool isxy  = (c < 2);
            const float e    = __expf(iswh ? x : -x);   // ONE transcendental
            const float sg   = rcpf(1.0f + e);
            const float gx   = (p != p0) ? gxBf : gxAf;
            const float gy   = (p != p0) ? gyBf : gyAf;
            const float g    = (c == 0) ? gx : gy;
            const float mul  = isxy ? STRIDE_F : (iswh ? ((c == 2) ? aw : ah) : 1.0f);
            const float add  = isxy ? g * STRIDE_F : 0.0f;
            res[k] = fmaf(iswh ? e : sg, mul, add);
            if (++c == NC) { c = 0; ++p; }
        }
        f4 o = {res[0], res[1], res[2], res[3]};
        *reinterpret_cast<f4*>(out_sub + e0) = o;       // regular store (L3-fit)
    }
}

__global__ __launch_bounds__(256) void det_kernel(const float* __restrict__ in,
                                                  float* __restrict__ out) {
    __shared__ __align__(16) float lds[SUB * NC];        // 10880 B -> 8 blk/CU

    const int bid   = blockIdx.x;                        // no swizzle (L3-fit)
    const int plane = bid / TPP;                         // b*NA + a
    const int tile  = bid - plane * TPP;
    const int a     = plane % NA;
    const int t     = threadIdx.x;
    const float aw = c_aw[a];
    const float ah = c_ah[a];

    const int pos0 = tile * NPB;                         // tail tile: 5760
    const float* in_plane  = in  + (size_t)plane * (NC * NPOS) + pos0;
    float*       out_block = out + (size_t)plane * (NPOS * NC) + (size_t)pos0 * NC;

    if (tile != TILES_MAIN) {                            // block-uniform branch
        f4 ra[3], rb[3];
        stage_load<8, 3>(in_plane,       t, ra);         // subtile A
        stage_load<8, 3>(in_plane + SUB, t, rb);         // subtile B — in flight
        stage_write<8, 3>(lds, t, ra);                   // waits only A's loads
        __syncthreads();
        compute_store<8, 3>(lds, out_block, pos0, aw, ah, t);   // B hides here
        __syncthreads();                                 // readers of A done
        stage_write<8, 3>(lds, t, rb);
        __syncthreads();
        compute_store<8, 3>(lds, out_block + SUB * NC, pos0 + SUB, aw, ah, t);
    } else {                                             // 16-position tail
        f4 ra[2];
        stage_load<4, 2>(in_plane, t, ra);
        stage_write<4, 2>(lds, t, ra);
        __syncthreads();
        compute_store<4, 2>(lds, out_block, pos0, aw, ah, t);
    }
}

extern "C" void kernel_launch(void* const* d_in, const int* in_sizes, int n_in,
                              void* d_out, int out_size, void* d_ws, size_t ws_size,
                              hipStream_t stream) {
    const float* x = (const float*)d_in[0];
    float* out     = (float*)d_out;
    const int nB     = in_sizes[0] / (NA * NC * NPOS);   // 16
    const int blocks = nB * NA * TPP;                    // 48 * 91 = 4368
    det_kernel<<<blocks, 256, 0, stream>>>(x, out);
}